// Round 10
// baseline (976.783 us; speedup 1.0000x reference)
//
#include <hip/hip_runtime.h>

#define HD 128
#define N_TX 200000
#define N_CARD 80000
#define N_EMAIL 60000
#define NE 250000
#define SEG_TX_TC 0
#define SEG_TX_TE 200000
#define SEG_CARD  400000
#define SEG_EMAIL 480000
#define NSEG 540000

typedef __attribute__((ext_vector_type(8))) short bf16x8;
typedef __attribute__((ext_vector_type(4))) float f32x4;

__device__ __forceinline__ ushort f2bf(float f) {
    uint u = __float_as_uint(f);
    u += 0x7FFFu + ((u >> 16) & 1u);
    return (ushort)(u >> 16);
}
__device__ __forceinline__ float bf2f(ushort h) {
    return __uint_as_float(((uint)h) << 16);
}

// ---------------------------------------------------------------------------
// MFMA GEMM, bf16x3 split: out = [relu]( A[M,K] @ W[K,128] (+bias) ).
// One wave owns 64 rows x all 128 cols (in-place safe: rows are
// wave-exclusive, all A reads precede the epilogue stores).
// W passed pre-split (hi/lo bf16) and pre-swizzled into fragment order:
//   elem(k,n) at [((ks*8+nt)*64 + lane)*8 + j], lane=((kk>>3)<<4)|(n&15),
//   j=kk&7, kk=k&31 — so a B-frag load is one coalesced dwordx4 per lane.
// Fragment maps (guide-verified): C/D col=lane&15,row=(lane>>4)*4+reg;
// A row=lane&15,k=(lane>>4)*8+j; B col=lane&15,k=(lane>>4)*8+j.
// ---------------------------------------------------------------------------
template <int KS>
__global__ __launch_bounds__(256) void mm_k(
    const float* __restrict__ A, const ushort* __restrict__ Fhi,
    const ushort* __restrict__ Flo, int M,
    const float* __restrict__ bias, int relu, float* __restrict__ out)
{
    const int K = KS * 32;
    int wid = threadIdx.x >> 6, lane = threadIdx.x & 63;
    int job = blockIdx.x * 4 + wid;
    int row0 = job * 64;
    if (row0 >= M) return;
    int l15 = lane & 15, lg = lane >> 4;

    f32x4 acc[4][8];
#pragma unroll
    for (int m = 0; m < 4; m++)
#pragma unroll
        for (int n = 0; n < 8; n++) acc[m][n] = (f32x4){0.f, 0.f, 0.f, 0.f};

#pragma unroll
    for (int ks = 0; ks < KS; ks++) {
        bf16x8 bh[8], bl[8];
#pragma unroll
        for (int nt = 0; nt < 8; nt++) {
            int o = ((ks * 8 + nt) * 64 + lane) * 8;
            bh[nt] = *(const bf16x8*)&Fhi[o];
            bl[nt] = *(const bf16x8*)&Flo[o];
        }
#pragma unroll
        for (int mt = 0; mt < 4; mt++) {
            int row = row0 + mt * 16 + l15;
            const float4* ap = (const float4*)(A + (long)row * K + ks * 32 + lg * 8);
            float4 z = make_float4(0.f, 0.f, 0.f, 0.f);
            float4 a0 = (row < M) ? ap[0] : z;
            float4 a1 = (row < M) ? ap[1] : z;
            float av[8] = {a0.x, a0.y, a0.z, a0.w, a1.x, a1.y, a1.z, a1.w};
            bf16x8 ah, al;
#pragma unroll
            for (int j = 0; j < 8; j++) {
                ushort hh = f2bf(av[j]);
                float r = av[j] - bf2f(hh);
                ah[j] = (short)hh;
                al[j] = (short)f2bf(r);
            }
#pragma unroll
            for (int nt = 0; nt < 8; nt++) {
                acc[mt][nt] = __builtin_amdgcn_mfma_f32_16x16x32_bf16(ah, bh[nt], acc[mt][nt], 0, 0, 0);
                acc[mt][nt] = __builtin_amdgcn_mfma_f32_16x16x32_bf16(al, bh[nt], acc[mt][nt], 0, 0, 0);
                acc[mt][nt] = __builtin_amdgcn_mfma_f32_16x16x32_bf16(ah, bl[nt], acc[mt][nt], 0, 0, 0);
            }
        }
    }

#pragma unroll
    for (int nt = 0; nt < 8; nt++) {
        float bv = bias ? bias[nt * 16 + l15] : 0.f;
#pragma unroll
        for (int mt = 0; mt < 4; mt++) {
#pragma unroll
            for (int r = 0; r < 4; r++) {
                int row = row0 + mt * 16 + lg * 4 + r;
                if (row < M) {
                    float v = acc[mt][nt][r] + bv;
                    if (relu) v = fmaxf(v, 0.f);
                    out[(long)row * 128 + nt * 16 + l15] = v;
                }
            }
        }
    }
}

// Split+swizzle all weight matrices into fragment-ordered hi/lo bf16 buffers.
// mats: 0=W_in(64x128) 1=Wl1[0] 2=Wl1[2] 3=Wr1[1]+Wr1[3] 4=Wl2[1] 5=Wl2[3]
//       6=Wr2[1]+Wr2[3].  Also folds bias sums.
__global__ __launch_bounds__(256) void prep2_k(
    const float* __restrict__ W_in, const float* __restrict__ Wl1,
    const float* __restrict__ bl1, const float* __restrict__ Wr1,
    const float* __restrict__ Wl2, const float* __restrict__ bl2,
    const float* __restrict__ Wr2,
    ushort* __restrict__ Fhi, ushort* __restrict__ Flo,
    float* __restrict__ bsum1, float* __restrict__ bsum2)
{
    int tid = blockIdx.x * 256 + threadIdx.x;
    if (tid < 128) {
        bsum1[tid] = bl1[128 + tid] + bl1[3 * 128 + tid];
        bsum2[tid] = bl2[128 + tid] + bl2[3 * 128 + tid];
    }
    if (tid >= 7 * 16384) return;
    int mat = tid >> 14, idx = tid & 16383;
    int k = idx >> 7, n = idx & 127;
    float v;
    switch (mat) {
        case 0: if (k >= 64) return; v = W_in[idx]; break;
        case 1: v = Wl1[0 * 16384 + idx]; break;
        case 2: v = Wl1[2 * 16384 + idx]; break;
        case 3: v = Wr1[1 * 16384 + idx] + Wr1[3 * 16384 + idx]; break;
        case 4: v = Wl2[1 * 16384 + idx]; break;
        case 5: v = Wl2[3 * 16384 + idx]; break;
        default: v = Wr2[1 * 16384 + idx] + Wr2[3 * 16384 + idx]; break;
    }
    int ks = k >> 5, kk = k & 31, nt = n >> 4;
    int lane = ((kk >> 3) << 4) | (n & 15), j = kk & 7;
    int off = ((ks * 8 + nt) * 64 + lane) * 8 + j;
    ushort h = f2bf(v);
    ushort lo = f2bf(v - bf2f(h));
    Fhi[mat * 16384 + off] = h;
    Flo[mat * 16384 + off] = lo;
}

// ---- CSR build ----
__global__ __launch_bounds__(256) void degree_k(
    const int* __restrict__ tc_src, const int* __restrict__ tc_dst,
    const int* __restrict__ te_src, const int* __restrict__ te_dst,
    int* deg, int E)
{
    int e = blockIdx.x * 256 + threadIdx.x;
    if (e >= E) return;
    atomicAdd(&deg[SEG_TX_TC + tc_src[e]], 1);
    atomicAdd(&deg[SEG_TX_TE + te_src[e]], 1);
    atomicAdd(&deg[SEG_CARD  + tc_dst[e]], 1);
    atomicAdd(&deg[SEG_EMAIL + te_dst[e]], 1);
}

__global__ __launch_bounds__(256) void scan1_k(const int* __restrict__ in,
                                               int* __restrict__ out,
                                               int* __restrict__ bsums, int n)
{
    __shared__ int lds[256];
    int b = blockIdx.x, t = threadIdx.x;
    int base = b * 1024 + t * 4;
    int4 v = make_int4(0, 0, 0, 0);
    if (base + 3 < n) v = *(const int4*)&in[base];
    else {
        if (base + 0 < n) v.x = in[base + 0];
        if (base + 1 < n) v.y = in[base + 1];
        if (base + 2 < n) v.z = in[base + 2];
    }
    int s = v.x + v.y + v.z + v.w;
    lds[t] = s;
    __syncthreads();
    for (int off = 1; off < 256; off <<= 1) {
        int val = (t >= off) ? lds[t - off] : 0;
        __syncthreads();
        lds[t] += val;
        __syncthreads();
    }
    int excl = lds[t] - s;
    if (t == 255) bsums[b] = lds[255];
    int p0 = excl, p1 = p0 + v.x, p2 = p1 + v.y, p3 = p2 + v.z;
    if (base + 0 < n) out[base + 0] = p0;
    if (base + 1 < n) out[base + 1] = p1;
    if (base + 2 < n) out[base + 2] = p2;
    if (base + 3 < n) out[base + 3] = p3;
}

__global__ __launch_bounds__(256) void scan2_k(int* bsums, int nb)
{
    __shared__ int lds[256];
    int t = threadIdx.x;
    int carry = 0;
    for (int start = 0; start < nb; start += 256) {
        int i = start + t;
        int s = (i < nb) ? bsums[i] : 0;
        lds[t] = s;
        __syncthreads();
        for (int off = 1; off < 256; off <<= 1) {
            int v = (t >= off) ? lds[t - off] : 0;
            __syncthreads();
            lds[t] += v;
            __syncthreads();
        }
        if (i < nb) bsums[i] = carry + lds[t] - s;
        carry += lds[255];
        __syncthreads();
    }
}

__global__ __launch_bounds__(256) void scan3_k(int* __restrict__ rowptr,
                                               int* __restrict__ cursor,
                                               const int* __restrict__ bsums, int n)
{
    int i = blockIdx.x * 256 + threadIdx.x;
    if (i < n) {
        int v = rowptr[i] + bsums[i >> 10];
        rowptr[i] = v;
        cursor[i] = v;
    }
}

__global__ __launch_bounds__(256) void fill_k(
    const int* __restrict__ tc_src, const int* __restrict__ tc_dst,
    const int* __restrict__ te_src, const int* __restrict__ te_dst,
    int* __restrict__ cursor, int* __restrict__ colidx, int E)
{
    int e = blockIdx.x * 256 + threadIdx.x;
    if (e >= E) return;
    int s = tc_src[e], d = tc_dst[e];
    int p = atomicAdd(&cursor[SEG_TX_TC + s], 1); colidx[p] = d;
    p = atomicAdd(&cursor[SEG_CARD + d], 1);      colidx[p] = s;
    s = te_src[e]; d = te_dst[e];
    p = atomicAdd(&cursor[SEG_TX_TE + s], 1);     colidx[p] = d;
    p = atomicAdd(&cursor[SEG_EMAIL + d], 1);     colidx[p] = s;
}

// out[d] = (1/max(deg,1)) * sum_{s in N(d)} vals[s]   — one wave per dst row
__global__ __launch_bounds__(256) void gather_mean_k(
    const float* __restrict__ vals, const int* __restrict__ rowptr,
    const int* __restrict__ deg, const int* __restrict__ colidx,
    float* __restrict__ out, int n)
{
    int w = (blockIdx.x * 256 + threadIdx.x) >> 6;
    if (w >= n) return;
    int lane = threadIdx.x & 63;
    int start = rowptr[w], dg = deg[w];
    float2 acc = make_float2(0.f, 0.f);
    for (int e = start; e < start + dg; ++e) {
        int s = colidx[e];
        float2 v = *(const float2*)&vals[(long)s * 128 + lane * 2];
        acc.x += v.x; acc.y += v.y;
    }
    float sc = 1.f / (float)max(dg, 1);
    *(float2*)&out[(long)w * 128 + lane * 2] = make_float2(acc.x * sc, acc.y * sc);
}

// Fused: final = B[w] + mean_tc(zC) + mean_te(zE); out[w]=relu(final)@Wc+bc
__global__ __launch_bounds__(256) void gather2_dot_k(
    const float* __restrict__ zC, const float* __restrict__ zE,
    const int* __restrict__ rowptr, const int* __restrict__ deg,
    const int* __restrict__ colidx, const float* __restrict__ B,
    const float* __restrict__ Wc, const float* __restrict__ bcp,
    float* __restrict__ out, int n)
{
    int w = (blockIdx.x * 256 + threadIdx.x) >> 6;
    if (w >= n) return;
    int lane = threadIdx.x & 63;
    float2 acc = *(const float2*)&B[(long)w * 128 + lane * 2];

    int start = rowptr[SEG_TX_TC + w], dg = deg[SEG_TX_TC + w];
    float2 a = make_float2(0.f, 0.f);
    for (int e = start; e < start + dg; ++e) {
        int s = colidx[e];
        float2 v = *(const float2*)&zC[(long)s * 128 + lane * 2];
        a.x += v.x; a.y += v.y;
    }
    float sc = 1.f / (float)max(dg, 1);
    acc.x += a.x * sc; acc.y += a.y * sc;

    start = rowptr[SEG_TX_TE + w]; dg = deg[SEG_TX_TE + w];
    a = make_float2(0.f, 0.f);
    for (int e = start; e < start + dg; ++e) {
        int s = colidx[e];
        float2 v = *(const float2*)&zE[(long)s * 128 + lane * 2];
        a.x += v.x; a.y += v.y;
    }
    sc = 1.f / (float)max(dg, 1);
    acc.x += a.x * sc; acc.y += a.y * sc;

    float2 c = *(const float2*)&Wc[lane * 2];
    float p = fmaxf(acc.x, 0.f) * c.x + fmaxf(acc.y, 0.f) * c.y;
#pragma unroll
    for (int off = 32; off > 0; off >>= 1) p += __shfl_xor(p, off);
    if (lane == 0) out[w] = p + bcp[0];
}

extern "C" void kernel_launch(void* const* d_in, const int* in_sizes, int n_in,
                              void* d_out, int out_size, void* d_ws, size_t ws_size,
                              hipStream_t stream)
{
    const float* x_tx  = (const float*)d_in[0];
    const float* W_in  = (const float*)d_in[1];
    const float* b_in  = (const float*)d_in[2];
    const float* Wl1   = (const float*)d_in[3];
    const float* bl1   = (const float*)d_in[4];
    const float* Wr1   = (const float*)d_in[5];
    const float* Wl2   = (const float*)d_in[6];
    const float* bl2   = (const float*)d_in[7];
    const float* Wr2   = (const float*)d_in[8];
    const float* Wc    = (const float*)d_in[9];
    const float* bc    = (const float*)d_in[10];
    const int* tc_src  = (const int*)d_in[11];
    const int* tc_dst  = (const int*)d_in[12];
    const int* te_src  = (const int*)d_in[13];
    const int* te_dst  = (const int*)d_in[14];

    char* ws = (char*)d_ws;
    size_t off = 0;
    auto alloc = [&](size_t n) { float* p = (float*)(ws + off); off += n * 4; return p; };
    float* B1   = alloc(25600000);   // N_TX*128: h_tx -> h1_tx -> base (in place)
    float* aggC = alloc(10240000);   // N_CARD*128: agg -> h1 -> z (in place)
    float* aggE = alloc(7680000);    // N_EMAIL*128
    float* bsum1 = alloc(128);
    float* bsum2 = alloc(128);
    int* deg    = (int*)(ws + off); off += (size_t)NSEG * 4;
    int* rowptr = (int*)(ws + off); off += (size_t)NSEG * 4;
    int* cursor = (int*)(ws + off); off += (size_t)NSEG * 4;
    int* colidx = (int*)(ws + off); off += (size_t)(4 * NE) * 4;
    int* bsums  = (int*)(ws + off); off += 1024 * 4;
    ushort* Fhi = (ushort*)(ws + off); off += (size_t)(7 * 16384) * 2;
    ushort* Flo = (ushort*)(ws + off); off += (size_t)(7 * 16384) * 2;

    const int NB = (NSEG + 1023) / 1024;

    // --- CSR build ---
    hipMemsetAsync(deg, 0, (size_t)NSEG * 4, stream);
    degree_k<<<(NE + 255) / 256, 256, 0, stream>>>(tc_src, tc_dst, te_src, te_dst, deg, NE);
    scan1_k<<<NB, 256, 0, stream>>>(deg, rowptr, bsums, NSEG);
    scan2_k<<<1, 256, 0, stream>>>(bsums, NB);
    scan3_k<<<(NSEG + 255) / 256, 256, 0, stream>>>(rowptr, cursor, bsums, NSEG);
    fill_k<<<(NE + 255) / 256, 256, 0, stream>>>(tc_src, tc_dst, te_src, te_dst,
                                                 cursor, colidx, NE);
    // --- weight split+swizzle ---
    prep2_k<<<(7 * 16384 + 255) / 256, 256, 0, stream>>>(
        W_in, Wl1, bl1, Wr1, Wl2, bl2, Wr2, Fhi, Flo, bsum1, bsum2);

    auto grid = [](int M) { return (((M + 63) / 64) + 3) / 4; };

    // --- input projection: B1 = x_tx @ W_in + b_in ---
    mm_k<2><<<grid(N_TX), 256, 0, stream>>>(x_tx, Fhi, Flo, N_TX, b_in, 0, B1);

    // --- layer 1 aggregation (gather, no atomics) ---
    gather_mean_k<<<(N_CARD * 64 + 255) / 256, 256, 0, stream>>>(
        B1, rowptr + SEG_CARD, deg + SEG_CARD, colidx, aggC, N_CARD);
    gather_mean_k<<<(N_EMAIL * 64 + 255) / 256, 256, 0, stream>>>(
        B1, rowptr + SEG_EMAIL, deg + SEG_EMAIL, colidx, aggE, N_EMAIL);

    // --- layer 1 linears (in place) ---
    mm_k<4><<<grid(N_CARD), 256, 0, stream>>>(aggC, Fhi + 1 * 16384, Flo + 1 * 16384,
                                              N_CARD, bl1 + 0 * 128, 1, aggC);
    mm_k<4><<<grid(N_EMAIL), 256, 0, stream>>>(aggE, Fhi + 2 * 16384, Flo + 2 * 16384,
                                               N_EMAIL, bl1 + 2 * 128, 1, aggE);
    mm_k<4><<<grid(N_TX), 256, 0, stream>>>(B1, Fhi + 3 * 16384, Flo + 3 * 16384,
                                            N_TX, bsum1, 1, B1);

    // --- layer 2: GEMM before aggregation (linear commutes w/ mean) ---
    mm_k<4><<<grid(N_CARD), 256, 0, stream>>>(aggC, Fhi + 4 * 16384, Flo + 4 * 16384,
                                              N_CARD, nullptr, 0, aggC);   // z_card
    mm_k<4><<<grid(N_EMAIL), 256, 0, stream>>>(aggE, Fhi + 5 * 16384, Flo + 5 * 16384,
                                               N_EMAIL, nullptr, 0, aggE); // z_email
    mm_k<4><<<grid(N_TX), 256, 0, stream>>>(B1, Fhi + 6 * 16384, Flo + 6 * 16384,
                                            N_TX, bsum2, 0, B1);           // base

    // --- fused dual gather + classifier dot ---
    gather2_dot_k<<<(N_TX * 64 + 255) / 256, 256, 0, stream>>>(
        aggC, aggE, rowptr, deg, colidx, B1, Wc, bc, (float*)d_out, N_TX);
}

// Round 11
// 657.564 us; speedup vs baseline: 1.4855x; 1.4855x over previous
//
#include <hip/hip_runtime.h>

#define HD 128
#define N_TX 200000
#define N_CARD 80000
#define N_EMAIL 60000
#define NE 250000
#define SEG_TX_TC 0
#define SEG_TX_TE 200000
#define SEG_CARD  400000
#define SEG_EMAIL 480000
#define NSEG 540000

typedef __attribute__((ext_vector_type(8))) short bf16x8;
typedef __attribute__((ext_vector_type(4))) float f32x4;

__device__ __forceinline__ ushort f2bf(float f) {
    uint u = __float_as_uint(f);
    u += 0x7FFFu + ((u >> 16) & 1u);
    return (ushort)(u >> 16);
}
__device__ __forceinline__ float bf2f(ushort h) {
    return __uint_as_float(((uint)h) << 16);
}

// ---------------------------------------------------------------------------
// MFMA GEMM, bf16x3 split, LDS-staged A: out = [relu](A[M,K]@W[K,128] (+bias)).
// Block = 4 independent waves, NO barrier. Wave w owns rows blk*64+w*16..+15:
// it stages its own 16 rows (16*K*4 B) via global_load_lds (1KB/instr,
// contiguous) and computes them. All M are multiples of 16 -> whole wave
// valid or exits; no OOB reads, no store masks. In-place safe (rows
// wave-exclusive, reads precede writes).
// LDS bank fix: physical chunk = logical chunk ^ (row&15). global_load_lds
// writes linearly, so the XOR is applied to the per-lane GLOBAL source
// address (G21 both-sides rule); ds_read applies the same XOR.
// W pre-split hi/lo bf16 in fragment order (same layout as r7, verified).
// ---------------------------------------------------------------------------
template <int KS>
__global__ __launch_bounds__(256) void mm_k(
    const float* __restrict__ A, const ushort* __restrict__ Fhi,
    const ushort* __restrict__ Flo, int M,
    const float* __restrict__ bias, int relu, float* __restrict__ out)
{
    const int K = KS * 32;           // 128 or 64
    const int ROWB = K * 4;          // row bytes: 512 or 256
    __shared__ float Alds[KS * 2048];  // 64 rows * K floats (32KB / 16KB)

    int wid = threadIdx.x >> 6, lane = threadIdx.x & 63;
    long wrow0 = (long)blockIdx.x * 64 + wid * 16;
    if (wrow0 >= M) return;
    int l15 = lane & 15, lg = lane >> 4;

    // ---- stage own 16 rows, source pre-swizzled ----
    const char* gbase = (const char*)(A + wrow0 * K);
    char* lbase = (char*)&Alds[wid * 16 * K];
#pragma unroll
    for (int i = 0; i < KS * 2; ++i) {
        int Dlin = i * 1024 + lane * 16;
        int row  = Dlin / ROWB;
        int cL   = (Dlin >> 4) & (KS * 8 - 1);
        int cG   = cL ^ row;                   // row&15 == row (row<16)
        __builtin_amdgcn_global_load_lds(
            (const __attribute__((address_space(1))) unsigned int*)
                (gbase + (long)row * ROWB + (cG << 4)),
            (__attribute__((address_space(3))) unsigned int*)(lbase + i * 1024),
            16, 0, 0);
    }
    asm volatile("s_waitcnt vmcnt(0)" ::: "memory");

    // ---- compute ----
    f32x4 acc[8];
#pragma unroll
    for (int n = 0; n < 8; n++) acc[n] = (f32x4){0.f, 0.f, 0.f, 0.f};

#pragma unroll
    for (int ks = 0; ks < KS; ++ks) {
        bf16x8 bh[8], bl[8];
#pragma unroll
        for (int nt = 0; nt < 8; nt++) {
            int o = ((ks * 8 + nt) * 64 + lane) * 8;
            bh[nt] = *(const bf16x8*)&Fhi[o];
            bl[nt] = *(const bf16x8*)&Flo[o];
        }
        int c0 = ks * 8 + lg * 2;
        float4 a0 = *(const float4*)(lbase + l15 * ROWB + ((c0 ^ l15) << 4));
        float4 a1 = *(const float4*)(lbase + l15 * ROWB + (((c0 + 1) ^ l15) << 4));
        float av[8] = {a0.x, a0.y, a0.z, a0.w, a1.x, a1.y, a1.z, a1.w};
        bf16x8 ah, al;
#pragma unroll
        for (int j = 0; j < 8; j++) {
            ushort hh = f2bf(av[j]);
            float r = av[j] - bf2f(hh);
            ah[j] = (short)hh;
            al[j] = (short)f2bf(r);
        }
#pragma unroll
        for (int nt = 0; nt < 8; nt++) {
            acc[nt] = __builtin_amdgcn_mfma_f32_16x16x32_bf16(ah, bh[nt], acc[nt], 0, 0, 0);
            acc[nt] = __builtin_amdgcn_mfma_f32_16x16x32_bf16(al, bh[nt], acc[nt], 0, 0, 0);
            acc[nt] = __builtin_amdgcn_mfma_f32_16x16x32_bf16(ah, bl[nt], acc[nt], 0, 0, 0);
        }
    }

    // ---- epilogue: C/D map col=l15, row=lg*4+r ----
#pragma unroll
    for (int nt = 0; nt < 8; nt++) {
        float bv = bias ? bias[nt * 16 + l15] : 0.f;
#pragma unroll
        for (int r = 0; r < 4; r++) {
            long row = wrow0 + lg * 4 + r;
            float v = acc[nt][r] + bv;
            if (relu) v = fmaxf(v, 0.f);
            out[row * 128 + nt * 16 + l15] = v;
        }
    }
}

// Split+swizzle weights into fragment-ordered hi/lo bf16 (layout verified r10).
// mats: 0=W_in(64x128) 1=Wl1[0] 2=Wl1[2] 3=Wr1[1]+Wr1[3] 4=Wl2[1] 5=Wl2[3]
//       6=Wr2[1]+Wr2[3].  Also folds bias sums.
__global__ __launch_bounds__(256) void prep2_k(
    const float* __restrict__ W_in, const float* __restrict__ Wl1,
    const float* __restrict__ bl1, const float* __restrict__ Wr1,
    const float* __restrict__ Wl2, const float* __restrict__ bl2,
    const float* __restrict__ Wr2,
    ushort* __restrict__ Fhi, ushort* __restrict__ Flo,
    float* __restrict__ bsum1, float* __restrict__ bsum2)
{
    int tid = blockIdx.x * 256 + threadIdx.x;
    if (tid < 128) {
        bsum1[tid] = bl1[128 + tid] + bl1[3 * 128 + tid];
        bsum2[tid] = bl2[128 + tid] + bl2[3 * 128 + tid];
    }
    if (tid >= 7 * 16384) return;
    int mat = tid >> 14, idx = tid & 16383;
    int k = idx >> 7, n = idx & 127;
    float v;
    switch (mat) {
        case 0: if (k >= 64) return; v = W_in[idx]; break;
        case 1: v = Wl1[0 * 16384 + idx]; break;
        case 2: v = Wl1[2 * 16384 + idx]; break;
        case 3: v = Wr1[1 * 16384 + idx] + Wr1[3 * 16384 + idx]; break;
        case 4: v = Wl2[1 * 16384 + idx]; break;
        case 5: v = Wl2[3 * 16384 + idx]; break;
        default: v = Wr2[1 * 16384 + idx] + Wr2[3 * 16384 + idx]; break;
    }
    int ks = k >> 5, kk = k & 31, nt = n >> 4;
    int lane = ((kk >> 3) << 4) | (n & 15), j = kk & 7;
    int off = ((ks * 8 + nt) * 64 + lane) * 8 + j;
    ushort h = f2bf(v);
    ushort lo = f2bf(v - bf2f(h));
    Fhi[mat * 16384 + off] = h;
    Flo[mat * 16384 + off] = lo;
}

// ---- CSR build ----
__global__ __launch_bounds__(256) void degree_k(
    const int* __restrict__ tc_src, const int* __restrict__ tc_dst,
    const int* __restrict__ te_src, const int* __restrict__ te_dst,
    int* deg, int E)
{
    int e = blockIdx.x * 256 + threadIdx.x;
    if (e >= E) return;
    atomicAdd(&deg[SEG_TX_TC + tc_src[e]], 1);
    atomicAdd(&deg[SEG_TX_TE + te_src[e]], 1);
    atomicAdd(&deg[SEG_CARD  + tc_dst[e]], 1);
    atomicAdd(&deg[SEG_EMAIL + te_dst[e]], 1);
}

__global__ __launch_bounds__(256) void scan1_k(const int* __restrict__ in,
                                               int* __restrict__ out,
                                               int* __restrict__ bsums, int n)
{
    __shared__ int lds[256];
    int b = blockIdx.x, t = threadIdx.x;
    int base = b * 1024 + t * 4;
    int4 v = make_int4(0, 0, 0, 0);
    if (base + 3 < n) v = *(const int4*)&in[base];
    else {
        if (base + 0 < n) v.x = in[base + 0];
        if (base + 1 < n) v.y = in[base + 1];
        if (base + 2 < n) v.z = in[base + 2];
    }
    int s = v.x + v.y + v.z + v.w;
    lds[t] = s;
    __syncthreads();
    for (int off = 1; off < 256; off <<= 1) {
        int val = (t >= off) ? lds[t - off] : 0;
        __syncthreads();
        lds[t] += val;
        __syncthreads();
    }
    int excl = lds[t] - s;
    if (t == 255) bsums[b] = lds[255];
    int p0 = excl, p1 = p0 + v.x, p2 = p1 + v.y, p3 = p2 + v.z;
    if (base + 0 < n) out[base + 0] = p0;
    if (base + 1 < n) out[base + 1] = p1;
    if (base + 2 < n) out[base + 2] = p2;
    if (base + 3 < n) out[base + 3] = p3;
}

__global__ __launch_bounds__(256) void scan2_k(int* bsums, int nb)
{
    __shared__ int lds[256];
    int t = threadIdx.x;
    int carry = 0;
    for (int start = 0; start < nb; start += 256) {
        int i = start + t;
        int s = (i < nb) ? bsums[i] : 0;
        lds[t] = s;
        __syncthreads();
        for (int off = 1; off < 256; off <<= 1) {
            int v = (t >= off) ? lds[t - off] : 0;
            __syncthreads();
            lds[t] += v;
            __syncthreads();
        }
        if (i < nb) bsums[i] = carry + lds[t] - s;
        carry += lds[255];
        __syncthreads();
    }
}

__global__ __launch_bounds__(256) void scan3_k(int* __restrict__ rowptr,
                                               int* __restrict__ cursor,
                                               const int* __restrict__ bsums, int n)
{
    int i = blockIdx.x * 256 + threadIdx.x;
    if (i < n) {
        int v = rowptr[i] + bsums[i >> 10];
        rowptr[i] = v;
        cursor[i] = v;
    }
}

__global__ __launch_bounds__(256) void fill_k(
    const int* __restrict__ tc_src, const int* __restrict__ tc_dst,
    const int* __restrict__ te_src, const int* __restrict__ te_dst,
    int* __restrict__ cursor, int* __restrict__ colidx, int E)
{
    int e = blockIdx.x * 256 + threadIdx.x;
    if (e >= E) return;
    int s = tc_src[e], d = tc_dst[e];
    int p = atomicAdd(&cursor[SEG_TX_TC + s], 1); colidx[p] = d;
    p = atomicAdd(&cursor[SEG_CARD + d], 1);      colidx[p] = s;
    s = te_src[e]; d = te_dst[e];
    p = atomicAdd(&cursor[SEG_TX_TE + s], 1);     colidx[p] = d;
    p = atomicAdd(&cursor[SEG_EMAIL + d], 1);     colidx[p] = s;
}

// out[d] = (1/max(deg,1)) * sum_{s in N(d)} vals[s]   — one wave per dst row
__global__ __launch_bounds__(256) void gather_mean_k(
    const float* __restrict__ vals, const int* __restrict__ rowptr,
    const int* __restrict__ deg, const int* __restrict__ colidx,
    float* __restrict__ out, int n)
{
    int w = (blockIdx.x * 256 + threadIdx.x) >> 6;
    if (w >= n) return;
    int lane = threadIdx.x & 63;
    int start = rowptr[w], dg = deg[w];
    float2 acc = make_float2(0.f, 0.f);
    for (int e = start; e < start + dg; ++e) {
        int s = colidx[e];
        float2 v = *(const float2*)&vals[(long)s * 128 + lane * 2];
        acc.x += v.x; acc.y += v.y;
    }
    float sc = 1.f / (float)max(dg, 1);
    *(float2*)&out[(long)w * 128 + lane * 2] = make_float2(acc.x * sc, acc.y * sc);
}

// Fused: final = B[w] + mean_tc(zC) + mean_te(zE); out[w]=relu(final)@Wc+bc
__global__ __launch_bounds__(256) void gather2_dot_k(
    const float* __restrict__ zC, const float* __restrict__ zE,
    const int* __restrict__ rowptr, const int* __restrict__ deg,
    const int* __restrict__ colidx, const float* __restrict__ B,
    const float* __restrict__ Wc, const float* __restrict__ bcp,
    float* __restrict__ out, int n)
{
    int w = (blockIdx.x * 256 + threadIdx.x) >> 6;
    if (w >= n) return;
    int lane = threadIdx.x & 63;
    float2 acc = *(const float2*)&B[(long)w * 128 + lane * 2];

    int start = rowptr[SEG_TX_TC + w], dg = deg[SEG_TX_TC + w];
    float2 a = make_float2(0.f, 0.f);
    for (int e = start; e < start + dg; ++e) {
        int s = colidx[e];
        float2 v = *(const float2*)&zC[(long)s * 128 + lane * 2];
        a.x += v.x; a.y += v.y;
    }
    float sc = 1.f / (float)max(dg, 1);
    acc.x += a.x * sc; acc.y += a.y * sc;

    start = rowptr[SEG_TX_TE + w]; dg = deg[SEG_TX_TE + w];
    a = make_float2(0.f, 0.f);
    for (int e = start; e < start + dg; ++e) {
        int s = colidx[e];
        float2 v = *(const float2*)&zE[(long)s * 128 + lane * 2];
        a.x += v.x; a.y += v.y;
    }
    sc = 1.f / (float)max(dg, 1);
    acc.x += a.x * sc; acc.y += a.y * sc;

    float2 c = *(const float2*)&Wc[lane * 2];
    float p = fmaxf(acc.x, 0.f) * c.x + fmaxf(acc.y, 0.f) * c.y;
#pragma unroll
    for (int off = 32; off > 0; off >>= 1) p += __shfl_xor(p, off);
    if (lane == 0) out[w] = p + bcp[0];
}

extern "C" void kernel_launch(void* const* d_in, const int* in_sizes, int n_in,
                              void* d_out, int out_size, void* d_ws, size_t ws_size,
                              hipStream_t stream)
{
    const float* x_tx  = (const float*)d_in[0];
    const float* W_in  = (const float*)d_in[1];
    const float* b_in  = (const float*)d_in[2];
    const float* Wl1   = (const float*)d_in[3];
    const float* bl1   = (const float*)d_in[4];
    const float* Wr1   = (const float*)d_in[5];
    const float* Wl2   = (const float*)d_in[6];
    const float* bl2   = (const float*)d_in[7];
    const float* Wr2   = (const float*)d_in[8];
    const float* Wc    = (const float*)d_in[9];
    const float* bc    = (const float*)d_in[10];
    const int* tc_src  = (const int*)d_in[11];
    const int* tc_dst  = (const int*)d_in[12];
    const int* te_src  = (const int*)d_in[13];
    const int* te_dst  = (const int*)d_in[14];

    char* ws = (char*)d_ws;
    size_t off = 0;
    auto alloc = [&](size_t n) { float* p = (float*)(ws + off); off += n * 4; return p; };
    float* B1   = alloc(25600000);   // N_TX*128: h_tx -> h1_tx -> base (in place)
    float* aggC = alloc(10240000);   // N_CARD*128: agg -> h1 -> z (in place)
    float* aggE = alloc(7680000);    // N_EMAIL*128 (tail-block overreads stay in ws)
    float* bsum1 = alloc(128);
    float* bsum2 = alloc(128);
    int* deg    = (int*)(ws + off); off += (size_t)NSEG * 4;
    int* rowptr = (int*)(ws + off); off += (size_t)NSEG * 4;
    int* cursor = (int*)(ws + off); off += (size_t)NSEG * 4;
    int* colidx = (int*)(ws + off); off += (size_t)(4 * NE) * 4;
    int* bsums  = (int*)(ws + off); off += 1024 * 4;
    ushort* Fhi = (ushort*)(ws + off); off += (size_t)(7 * 16384) * 2;
    ushort* Flo = (ushort*)(ws + off); off += (size_t)(7 * 16384) * 2;

    const int NB = (NSEG + 1023) / 1024;

    // --- CSR build ---
    hipMemsetAsync(deg, 0, (size_t)NSEG * 4, stream);
    degree_k<<<(NE + 255) / 256, 256, 0, stream>>>(tc_src, tc_dst, te_src, te_dst, deg, NE);
    scan1_k<<<NB, 256, 0, stream>>>(deg, rowptr, bsums, NSEG);
    scan2_k<<<1, 256, 0, stream>>>(bsums, NB);
    scan3_k<<<(NSEG + 255) / 256, 256, 0, stream>>>(rowptr, cursor, bsums, NSEG);
    fill_k<<<(NE + 255) / 256, 256, 0, stream>>>(tc_src, tc_dst, te_src, te_dst,
                                                 cursor, colidx, NE);
    // --- weight split+swizzle ---
    prep2_k<<<(7 * 16384 + 255) / 256, 256, 0, stream>>>(
        W_in, Wl1, bl1, Wr1, Wl2, bl2, Wr2, Fhi, Flo, bsum1, bsum2);

    auto grid = [](int M) { return (M + 63) / 64; };

    // --- input projection: B1 = x_tx @ W_in + b_in ---
    mm_k<2><<<grid(N_TX), 256, 0, stream>>>(x_tx, Fhi, Flo, N_TX, b_in, 0, B1);

    // --- layer 1 aggregation (gather, no atomics) ---
    gather_mean_k<<<(N_CARD * 64 + 255) / 256, 256, 0, stream>>>(
        B1, rowptr + SEG_CARD, deg + SEG_CARD, colidx, aggC, N_CARD);
    gather_mean_k<<<(N_EMAIL * 64 + 255) / 256, 256, 0, stream>>>(
        B1, rowptr + SEG_EMAIL, deg + SEG_EMAIL, colidx, aggE, N_EMAIL);

    // --- layer 1 linears (in place) ---
    mm_k<4><<<grid(N_CARD), 256, 0, stream>>>(aggC, Fhi + 1 * 16384, Flo + 1 * 16384,
                                              N_CARD, bl1 + 0 * 128, 1, aggC);
    mm_k<4><<<grid(N_EMAIL), 256, 0, stream>>>(aggE, Fhi + 2 * 16384, Flo + 2 * 16384,
                                               N_EMAIL, bl1 + 2 * 128, 1, aggE);
    mm_k<4><<<grid(N_TX), 256, 0, stream>>>(B1, Fhi + 3 * 16384, Flo + 3 * 16384,
                                            N_TX, bsum1, 1, B1);

    // --- layer 2: GEMM before aggregation (linear commutes w/ mean) ---
    mm_k<4><<<grid(N_CARD), 256, 0, stream>>>(aggC, Fhi + 4 * 16384, Flo + 4 * 16384,
                                              N_CARD, nullptr, 0, aggC);   // z_card
    mm_k<4><<<grid(N_EMAIL), 256, 0, stream>>>(aggE, Fhi + 5 * 16384, Flo + 5 * 16384,
                                               N_EMAIL, nullptr, 0, aggE); // z_email
    mm_k<4><<<grid(N_TX), 256, 0, stream>>>(B1, Fhi + 6 * 16384, Flo + 6 * 16384,
                                            N_TX, bsum2, 0, B1);           // base

    // --- fused dual gather + classifier dot ---
    gather2_dot_k<<<(N_TX * 64 + 255) / 256, 256, 0, stream>>>(
        aggC, aggE, rowptr, deg, colidx, B1, Wc, bc, (float*)d_out, N_TX);
}